// Round 3
// baseline (1310.103 us; speedup 1.0000x reference)
//
#include <hip/hip_runtime.h>

typedef unsigned int u32;
typedef unsigned short u16;

constexpr int N_ATOMS   = 50000;
constexpr int N_BONDS   = 100000;
constexpr int MAX_NB    = 6;
constexpr int ATOM_FDIM = 133;
constexpr int BOND_FDIM = 147;
constexpr int HIDDEN    = 512;
constexpr int DEPTH     = 5;
constexpr int N_MOLS    = 2048;
constexpr int KB_PAD    = 160;   // f_bonds K padded to mult of 32
constexpr int KC        = 672;   // combined K: 160 (Wi) + 512 (Wh); also pads 645

typedef short bf16x8 __attribute__((ext_vector_type(8)));
typedef float f32x4  __attribute__((ext_vector_type(4)));

__device__ __forceinline__ float b2f(u32 u) {
    u <<= 16; float f; __builtin_memcpy(&f, &u, 4); return f;
}
__device__ __forceinline__ u16 f2b(float f) {
    u32 u; __builtin_memcpy(&u, &f, 4);
    u = (u + 0x7fffu + ((u >> 16) & 1u)) >> 16;
    return (u16)u;
}
__device__ __forceinline__ u32 pack2(float x, float y) {
    return (u32)f2b(x) | ((u32)f2b(y) << 16);
}
// read input element i as float; bf=1 -> data is bf16, bf=0 -> data is f32
__device__ __forceinline__ float load_in(const void* p, size_t i, u32 bf) {
    return bf ? b2f((u32)((const u16*)p)[i]) : ((const float*)p)[i];
}

// detect input dtype from f_bonds bit patterns (N(0,1) data)
__global__ void k_detect(const void* fb, u32* flag) {
    if (threadIdx.x == 0 && blockIdx.x == 0) {
        const u16* p = (const u16*)fb;
        int cnt = 0;
        for (int i = 0; i < 64; ++i) {
            const u32 e = (p[i] >> 7) & 0xFF;
            if (e >= 110 && e <= 140) ++cnt;
        }
        *flag = (cnt >= 52) ? 1u : 0u;   // 1 = inputs are bf16
    }
}

// ---------------------------------------------------------------------------
// MFMA GEMM: C[M,512] = A[M,K] @ B[K,512], B transposed (BT[512,ldb]), bf16.
// 128x128 tile, BK=32, 256 threads (4 waves 2x2), register->LDS staging.
// SPLIT: A cols [0,160) from A (lda ldaA), [160,K) from A2 (lda 512).
// MODE 0: out = relu(C)      MODE 1: out = relu(C + bias[col])
// ---------------------------------------------------------------------------
template <int SPLIT, int MODE>
__global__ void gemm_bt(const u16* __restrict__ A, int ldaA,
                        const u16* __restrict__ A2,
                        const u16* __restrict__ BT, int ldb,
                        const u16* __restrict__ bias,
                        u16* __restrict__ out,
                        int M, int K)
{
    __shared__ u16 As[128 * 32];
    __shared__ u16 Bs[128 * 32];
    const int t    = threadIdx.x;
    const int w    = t >> 6;
    const int l    = t & 63;
    const int quad = l >> 4;
    const int lr   = l & 15;
    const int bm0  = blockIdx.x * 128;
    const int bn0  = blockIdx.y * 128;
    const int wr   = (w >> 1) * 64;
    const int wc   = (w & 1) * 64;

    f32x4 acc[4][4];
#pragma unroll
    for (int i = 0; i < 4; ++i)
#pragma unroll
        for (int j = 0; j < 4; ++j) acc[i][j] = (f32x4){0.f, 0.f, 0.f, 0.f};

    const int kt_n = K >> 5;
    for (int kt = 0; kt < kt_n; ++kt) {
        const int k0 = kt << 5;
        const u16* srcA;
        int lda, kcol;
        if (SPLIT && kt >= 5) { srcA = A2; lda = HIDDEN; kcol = k0 - KB_PAD; }
        else                  { srcA = A;  lda = ldaA;   kcol = k0; }
        __syncthreads();   // previous tile's LDS reads done before overwrite
        // stage A tile [128 x 32] and BT tile [128 x 32] via registers.
        // chunk c (16 B): row r=c>>2, k-group c&3; LDS linear = c*16 B.
#pragma unroll
        for (int p = 0; p < 2; ++p) {
            const int c  = p * 256 + t;
            const int r  = c >> 2;
            const int kg = c & 3;
            int rowA = bm0 + r; if (rowA >= M) rowA = M - 1;
            const uint4 va = *(const uint4*)(srcA + (size_t)rowA * lda + kcol + kg * 8);
            const int rowB = bn0 + r;          // always < 512
            const uint4 vb = *(const uint4*)(BT + (size_t)rowB * ldb + k0 + kg * 8);
            *(uint4*)(As + c * 8) = va;
            *(uint4*)(Bs + c * 8) = vb;
        }
        __syncthreads();

        bf16x8 af[4], bfr[4];
#pragma unroll
        for (int i = 0; i < 4; ++i) {
            af[i]  = *(const bf16x8*)(As + (wr + i * 16 + lr) * 32 + quad * 8);
            bfr[i] = *(const bf16x8*)(Bs + (wc + i * 16 + lr) * 32 + quad * 8);
        }
#pragma unroll
        for (int i = 0; i < 4; ++i)
#pragma unroll
            for (int j = 0; j < 4; ++j)
                acc[i][j] = __builtin_amdgcn_mfma_f32_16x16x32_bf16(
                    af[i], bfr[j], acc[i][j], 0, 0, 0);
    }

    // epilogue: D row=(quad*4+reg), col=lr within each 16x16 subtile
#pragma unroll
    for (int i = 0; i < 4; ++i) {
        const int row0 = bm0 + wr + i * 16 + quad * 4;
#pragma unroll
        for (int j = 0; j < 4; ++j) {
            const int col = bn0 + wc + j * 16 + lr;
#pragma unroll
            for (int r = 0; r < 4; ++r) {
                const int row = row0 + r;
                if (row < M) {
                    float v = acc[i][j][r];
                    if (MODE == 1) v += b2f((u32)bias[col]);
                    out[(size_t)row * HIDDEN + col] = f2b(v > 0.f ? v : 0.f);
                }
            }
        }
    }
}

// pad+convert f_bonds [N_BONDS,147] -> bf16 [N_BONDS,160]
__global__ void k_pad_bonds(const void* __restrict__ src,
                            u16* __restrict__ dst,
                            const u32* __restrict__ flag)
{
    const u32 bf = *flag;
    const int idx = blockIdx.x * 256 + threadIdx.x;
    if (idx >= N_BONDS * KB_PAD) return;
    const int b = idx / KB_PAD, k = idx - b * KB_PAD;
    dst[idx] = (k < BOND_FDIM) ? f2b(load_in(src, (size_t)b * BOND_FDIM + k, bf))
                               : (u16)0;
}

// WcT[n*672 + k] = k<147 ? W_i[k,n] : k<160 ? 0 : W_h[k-160,n]   (bf16)
__global__ void k_wcT(const void* __restrict__ wi,
                      const void* __restrict__ wh,
                      u16* __restrict__ wt,
                      const u32* __restrict__ flag)
{
    const u32 bf = *flag;
    const int idx = blockIdx.x * 256 + threadIdx.x;
    if (idx >= 512 * KC) return;
    const int n = idx / KC, k = idx - n * KC;
    float v = 0.f;
    if (k < BOND_FDIM)    v = load_in(wi, (size_t)k * HIDDEN + n, bf);
    else if (k >= KB_PAD) v = load_in(wh, (size_t)(k - KB_PAD) * HIDDEN + n, bf);
    wt[idx] = f2b(v);
}

// WoT[n*672 + k] = k<645 ? W_o[k,n] : 0   (bf16)
__global__ void k_woT(const void* __restrict__ wo,
                      u16* __restrict__ wt,
                      const u32* __restrict__ flag)
{
    const u32 bf = *flag;
    const int idx = blockIdx.x * 256 + threadIdx.x;
    if (idx >= 512 * KC) return;
    const int n = idx / KC, k = idx - n * KC;
    wt[idx] = (k < ATOM_FDIM + HIDDEN)
                ? f2b(load_in(wo, (size_t)k * HIDDEN + n, bf)) : (u16)0;
}

// bias -> bf16
__global__ void k_bias(const void* __restrict__ b, u16* __restrict__ dst,
                       const u32* __restrict__ flag)
{
    const u32 bf = *flag;
    const int i = threadIdx.x + blockIdx.x * 256;
    if (i < HIDDEN) dst[i] = f2b(load_in(b, i, bf));
}

__device__ __forceinline__ void acc_row(float* acc, const uint4 v, float s) {
    acc[0] += s * b2f(v.x & 0xffffu); acc[1] += s * b2f(v.x >> 16);
    acc[2] += s * b2f(v.y & 0xffffu); acc[3] += s * b2f(v.y >> 16);
    acc[4] += s * b2f(v.z & 0xffffu); acc[5] += s * b2f(v.z >> 16);
    acc[6] += s * b2f(v.w & 0xffffu); acc[7] += s * b2f(v.w >> 16);
}

// pre[b,:] = sum_j message[a2b[b2a[b],j],:] - message[b2revb[b],:]
__global__ void k_pre(const u16* __restrict__ message,
                      const int* __restrict__ a2b,
                      const int* __restrict__ b2a,
                      const int* __restrict__ b2revb,
                      u16* __restrict__ pre)
{
    const int b = blockIdx.x * 4 + (threadIdx.x >> 6);
    const int l = threadIdx.x & 63;
    const int a  = b2a[b];
    const int rb = b2revb[b];
    float acc[8] = {0.f, 0.f, 0.f, 0.f, 0.f, 0.f, 0.f, 0.f};
    acc_row(acc, *(const uint4*)(message + (size_t)rb * HIDDEN + l * 8), -1.f);
#pragma unroll
    for (int j = 0; j < MAX_NB; ++j) {
        const int nb = a2b[a * MAX_NB + j];
        acc_row(acc, *(const uint4*)(message + (size_t)nb * HIDDEN + l * 8), 1.f);
    }
    uint4 o;
    o.x = pack2(acc[0], acc[1]); o.y = pack2(acc[2], acc[3]);
    o.z = pack2(acc[4], acc[5]); o.w = pack2(acc[6], acc[7]);
    *(uint4*)(pre + (size_t)b * HIDDEN + l * 8) = o;
}

// amsg[a,:] = sum_j message[a2b[a,j],:]
__global__ void k_amsg(const u16* __restrict__ message,
                       const int* __restrict__ a2b,
                       u16* __restrict__ amsg)
{
    const int a = blockIdx.x * 4 + (threadIdx.x >> 6);
    const int l = threadIdx.x & 63;
    float acc[8] = {0.f, 0.f, 0.f, 0.f, 0.f, 0.f, 0.f, 0.f};
#pragma unroll
    for (int j = 0; j < MAX_NB; ++j) {
        const int nb = a2b[a * MAX_NB + j];
        acc_row(acc, *(const uint4*)(message + (size_t)nb * HIDDEN + l * 8), 1.f);
    }
    uint4 o;
    o.x = pack2(acc[0], acc[1]); o.y = pack2(acc[2], acc[3]);
    o.z = pack2(acc[4], acc[5]); o.w = pack2(acc[6], acc[7]);
    *(uint4*)(amsg + (size_t)a * HIDDEN + l * 8) = o;
}

// ain[a, 0:133]=f_atoms (converted), [133:645]=amsg, [645:672]=0   (bf16)
__global__ void k_concat(const void* __restrict__ f_atoms,
                         const u16* __restrict__ amsg,
                         u16* __restrict__ ain,
                         const u32* __restrict__ flag)
{
    const u32 bf = *flag;
    const int idx = blockIdx.x * 256 + threadIdx.x;
    if (idx >= N_ATOMS * KC) return;
    const int a = idx / KC, c = idx - a * KC;
    u16 v;
    if (c < ATOM_FDIM)               v = f2b(load_in(f_atoms, (size_t)a * ATOM_FDIM + c, bf));
    else if (c < ATOM_FDIM + HIDDEN) v = amsg[(size_t)a * HIDDEN + (c - ATOM_FDIM)];
    else                             v = 0;
    ain[idx] = v;
}

// per-mol mean over sorted mol_ids; output dtype per flag
__global__ void k_mean(const u16* __restrict__ ah,
                       const int* __restrict__ mol_ids,
                       void* __restrict__ out,
                       const u32* __restrict__ flag)
{
    const u32 bf = *flag;
    const int m = blockIdx.x, t = threadIdx.x;
    int lo = 0, hi = N_ATOMS;
    while (lo < hi) { const int mid = (lo + hi) >> 1; if (mol_ids[mid] < m) lo = mid + 1; else hi = mid; }
    const int start = lo;
    hi = N_ATOMS;
    while (lo < hi) { const int mid = (lo + hi) >> 1; if (mol_ids[mid] <= m) lo = mid + 1; else hi = mid; }
    const int end = lo;
    float x = 0.f, y = 0.f;
    for (int a = start; a < end; ++a) {
        const u32 p = *(const u32*)(ah + (size_t)a * HIDDEN + t * 2);
        x += b2f(p & 0xffffu); y += b2f(p >> 16);
    }
    const float inv = (end > start) ? 1.f / (float)(end - start) : 0.f;
    x *= inv; y *= inv;
    if (bf) {
        *(u32*)((u16*)out + (size_t)m * HIDDEN + t * 2) = pack2(x, y);
    } else {
        float* o = (float*)out + (size_t)m * HIDDEN + t * 2;
        o[0] = x; o[1] = y;
    }
}

extern "C" void kernel_launch(void* const* d_in, const int* in_sizes, int n_in,
                              void* d_out, int out_size, void* d_ws, size_t ws_size,
                              hipStream_t stream)
{
    const void* f_atoms = d_in[0];
    const void* f_bonds = d_in[1];
    const int* a2b     = (const int*)d_in[2];
    const int* b2a     = (const int*)d_in[3];
    const int* b2revb  = (const int*)d_in[4];
    const int* mol_ids = (const int*)d_in[5];
    const void* W_i = d_in[6];
    const void* W_h = d_in[7];
    const void* W_o = d_in[8];
    const void* b_o = d_in[9];

    char* ws = (char*)d_ws;
    size_t off = 0;
    auto alloc = [&](size_t bytes) -> char* {
        char* p = ws + off;
        off += (bytes + 255) & ~(size_t)255;
        return p;
    };
    u32* flag     = (u32*)alloc(256);
    u16* biasB    = (u16*)alloc((size_t)HIDDEN * 2);
    u16* WcT      = (u16*)alloc((size_t)512 * KC * 2);         //  0.69 MB
    u16* WoT      = (u16*)alloc((size_t)512 * KC * 2);         //  0.69 MB
    u16* fbpad    = (u16*)alloc((size_t)N_BONDS * KB_PAD * 2); // 32.0 MB
    u16* pre      = (u16*)alloc((size_t)N_BONDS * HIDDEN * 2); //102.4 MB
    u16* message  = (u16*)alloc((size_t)N_BONDS * HIDDEN * 2); //102.4 MB
    // total ~238.2 MB. Aliases (lifetimes disjoint):
    u16* amsgF = pre;                            // final amsg [50000,512]
    u16* ah    = pre + (size_t)N_ATOMS * HIDDEN; // atom_hiddens, upper half of pre
    u16* ain   = message;                        // [50000,672]

    k_detect<<<dim3(1), 64, 0, stream>>>(f_bonds, flag);
    k_wcT<<<dim3((512 * KC + 255) / 256), 256, 0, stream>>>(W_i, W_h, WcT, flag);
    k_woT<<<dim3((512 * KC + 255) / 256), 256, 0, stream>>>(W_o, WoT, flag);
    k_bias<<<dim3(2), 256, 0, stream>>>(b_o, biasB, flag);
    k_pad_bonds<<<dim3((N_BONDS * KB_PAD + 255) / 256), 256, 0, stream>>>(f_bonds, fbpad, flag);

    const dim3 gB((N_BONDS + 127) / 128, 4);
    // message = relu(f_bonds @ W_i)
    gemm_bt<1, 0><<<gB, 256, 0, stream>>>(fbpad, KB_PAD, pre, WcT, KC, nullptr,
                                          message, N_BONDS, KB_PAD);
    for (int d = 0; d < DEPTH - 1; ++d) {
        k_pre<<<dim3(N_BONDS / 4), 256, 0, stream>>>(message, a2b, b2a, b2revb, pre);
        // message = relu([fb | pre] @ [Wi ; Wh]) = relu(inp + pre @ W_h)
        gemm_bt<1, 0><<<gB, 256, 0, stream>>>(fbpad, KB_PAD, pre, WcT, KC, nullptr,
                                              message, N_BONDS, KC);
    }
    k_amsg<<<dim3(N_ATOMS / 4), 256, 0, stream>>>(message, a2b, amsgF);
    k_concat<<<dim3((N_ATOMS * KC + 255) / 256), 256, 0, stream>>>(f_atoms, amsgF, ain, flag);
    // atom_hiddens = relu(a_input @ W_o + b_o)
    gemm_bt<0, 1><<<dim3((N_ATOMS + 127) / 128, 4), 256, 0, stream>>>(
        ain, KC, nullptr, WoT, KC, biasB, ah, N_ATOMS, KC);
    k_mean<<<dim3(N_MOLS), 256, 0, stream>>>(ah, mol_ids, d_out, flag);
}

// Round 4
// 1248.796 us; speedup vs baseline: 1.0491x; 1.0491x over previous
//
#include <hip/hip_runtime.h>

typedef unsigned int u32;
typedef unsigned short u16;

constexpr int N_ATOMS   = 50000;
constexpr int N_BONDS   = 100000;
constexpr int MAX_NB    = 6;
constexpr int ATOM_FDIM = 133;
constexpr int BOND_FDIM = 147;
constexpr int HIDDEN    = 512;
constexpr int DEPTH     = 5;
constexpr int N_MOLS    = 2048;
constexpr int KB_PAD    = 160;   // f_bonds K padded to mult of 32
constexpr int KC        = 672;   // combined K: 160 (Wi) + 512 (Wh); also 512+133 pad

typedef short bf16x8 __attribute__((ext_vector_type(8)));
typedef float f32x4  __attribute__((ext_vector_type(4)));

__device__ __forceinline__ float b2f(u32 u) {
    u <<= 16; float f; __builtin_memcpy(&f, &u, 4); return f;
}
__device__ __forceinline__ u16 f2b(float f) {
    u32 u; __builtin_memcpy(&u, &f, 4);
    u = (u + 0x7fffu + ((u >> 16) & 1u)) >> 16;
    return (u16)u;
}
__device__ __forceinline__ u32 pack2(float x, float y) {
    return (u32)f2b(x) | ((u32)f2b(y) << 16);
}
// read input element i as float; bf=1 -> data is bf16, bf=0 -> data is f32
__device__ __forceinline__ float load_in(const void* p, size_t i, u32 bf) {
    return bf ? b2f((u32)((const u16*)p)[i]) : ((const float*)p)[i];
}

// detect input dtype from f_bonds bit patterns (N(0,1) data)
__global__ void k_detect(const void* fb, u32* flag) {
    if (threadIdx.x == 0 && blockIdx.x == 0) {
        const u16* p = (const u16*)fb;
        int cnt = 0;
        for (int i = 0; i < 64; ++i) {
            const u32 e = (p[i] >> 7) & 0xFF;
            if (e >= 110 && e <= 140) ++cnt;
        }
        *flag = (cnt >= 52) ? 1u : 0u;   // 1 = inputs are bf16
    }
}

// ---------------------------------------------------------------------------
// MFMA GEMM: C[M,512] = A[M,K] @ B[K,512], B transposed (BT[512,ldb]), bf16.
// 128x128 tile, BK=32, 256 threads (4 waves 2x2).
// Staging via global_load_lds width=16 (m97 recipe, wave-uniform LDS base).
// Grid: blockIdx.x = N-tile (fast axis -> A-slab L2/L3 reuse), .y = M-tile.
// SPLIT: A cols [0,160) from A (lda ldaA), [160,K) from A2 (lda 512).
// MODE 0: out = relu(C)      MODE 1: out = relu(C + bias[col])
// ---------------------------------------------------------------------------
template <int SPLIT, int MODE>
__global__ void gemm_bt(const u16* __restrict__ A, int ldaA,
                        const u16* __restrict__ A2,
                        const u16* __restrict__ BT, int ldb,
                        const u16* __restrict__ bias,
                        u16* __restrict__ out,
                        int M, int K)
{
    __shared__ u16 As[128 * 32];
    __shared__ u16 Bs[128 * 32];
    const int t    = threadIdx.x;
    const int w    = t >> 6;
    const int l    = t & 63;
    const int quad = l >> 4;
    const int lr   = l & 15;
    const int bn0  = blockIdx.x * 128;
    const int bm0  = blockIdx.y * 128;
    const int wr   = (w >> 1) * 64;
    const int wc   = (w & 1) * 64;

    f32x4 acc[4][4];
#pragma unroll
    for (int i = 0; i < 4; ++i)
#pragma unroll
        for (int j = 0; j < 4; ++j) acc[i][j] = (f32x4){0.f, 0.f, 0.f, 0.f};

    const int kt_n = K >> 5;
    for (int kt = 0; kt < kt_n; ++kt) {
        const int k0 = kt << 5;
        const u16* srcA;
        int lda, kcol;
        if (SPLIT && kt >= 5) { srcA = A2; lda = HIDDEN; kcol = k0 - KB_PAD; }
        else                  { srcA = A;  lda = ldaA;   kcol = k0; }
        __syncthreads();   // previous tile's LDS reads done before overwrite
        // chunk c (16 B): row r=c>>2, k-group c&3; LDS linear = c*16 B.
        // LDS dest = wave-uniform base (cj*1024 B) + lane*16 (HW rule).
#pragma unroll
        for (int j = 0; j < 2; ++j) {
            const int cj = w + j * 4;          // wave-uniform chunk group 0..7
            const int c  = cj * 64 + l;
            const int r  = c >> 2;
            const int kg = c & 3;
            int rowA = bm0 + r; if (rowA >= M) rowA = M - 1;
            const u16* ga = srcA + (size_t)rowA * lda + kcol + kg * 8;
            __builtin_amdgcn_global_load_lds(
                (const __attribute__((address_space(1))) void*)ga,
                (__attribute__((address_space(3))) void*)(As + cj * 512),
                16, 0, 0);
            const int rowB = bn0 + r;          // always < 512
            const u16* gb = BT + (size_t)rowB * ldb + k0 + kg * 8;
            __builtin_amdgcn_global_load_lds(
                (const __attribute__((address_space(1))) void*)gb,
                (__attribute__((address_space(3))) void*)(Bs + cj * 512),
                16, 0, 0);
        }
        __syncthreads();

        bf16x8 af[4], bfr[4];
#pragma unroll
        for (int i = 0; i < 4; ++i) {
            af[i]  = *(const bf16x8*)(As + (wr + i * 16 + lr) * 32 + quad * 8);
            bfr[i] = *(const bf16x8*)(Bs + (wc + i * 16 + lr) * 32 + quad * 8);
        }
#pragma unroll
        for (int i = 0; i < 4; ++i)
#pragma unroll
            for (int j = 0; j < 4; ++j)
                acc[i][j] = __builtin_amdgcn_mfma_f32_16x16x32_bf16(
                    af[i], bfr[j], acc[i][j], 0, 0, 0);
    }

    // epilogue: D row=(quad*4+reg), col=lr within each 16x16 subtile
#pragma unroll
    for (int i = 0; i < 4; ++i) {
        const int row0 = bm0 + wr + i * 16 + quad * 4;
#pragma unroll
        for (int j = 0; j < 4; ++j) {
            const int col = bn0 + wc + j * 16 + lr;
#pragma unroll
            for (int r = 0; r < 4; ++r) {
                const int row = row0 + r;
                if (row < M) {
                    float v = acc[i][j][r];
                    if (MODE == 1) v += b2f((u32)bias[col]);
                    out[(size_t)row * HIDDEN + col] = f2b(v > 0.f ? v : 0.f);
                }
            }
        }
    }
}

// pad+convert f_bonds [N_BONDS,147] -> bf16 [N_BONDS,160]
__global__ void k_pad_bonds(const void* __restrict__ src,
                            u16* __restrict__ dst,
                            const u32* __restrict__ flag)
{
    const u32 bf = *flag;
    const int idx = blockIdx.x * 256 + threadIdx.x;
    if (idx >= N_BONDS * KB_PAD) return;
    const int b = idx / KB_PAD, k = idx - b * KB_PAD;
    dst[idx] = (k < BOND_FDIM) ? f2b(load_in(src, (size_t)b * BOND_FDIM + k, bf))
                               : (u16)0;
}

// WcT[n*672 + k] = k<147 ? W_i[k,n] : k<160 ? 0 : W_h[k-160,n]   (bf16)
__global__ void k_wcT(const void* __restrict__ wi,
                      const void* __restrict__ wh,
                      u16* __restrict__ wt,
                      const u32* __restrict__ flag)
{
    const u32 bf = *flag;
    const int idx = blockIdx.x * 256 + threadIdx.x;
    if (idx >= 512 * KC) return;
    const int n = idx / KC, k = idx - n * KC;
    float v = 0.f;
    if (k < BOND_FDIM)    v = load_in(wi, (size_t)k * HIDDEN + n, bf);
    else if (k >= KB_PAD) v = load_in(wh, (size_t)(k - KB_PAD) * HIDDEN + n, bf);
    wt[idx] = f2b(v);
}

// W_o rows permuted to match ain = [amsg(512) | f_atoms(133) | pad(27)]:
// WoT[n*672+k] = k<512 ? W_o[133+k, n] : k<645 ? W_o[k-512, n] : 0
__global__ void k_woT(const void* __restrict__ wo,
                      u16* __restrict__ wt,
                      const u32* __restrict__ flag)
{
    const u32 bf = *flag;
    const int idx = blockIdx.x * 256 + threadIdx.x;
    if (idx >= 512 * KC) return;
    const int n = idx / KC, k = idx - n * KC;
    float v = 0.f;
    if (k < HIDDEN)                  v = load_in(wo, (size_t)(ATOM_FDIM + k) * HIDDEN + n, bf);
    else if (k < HIDDEN + ATOM_FDIM) v = load_in(wo, (size_t)(k - HIDDEN) * HIDDEN + n, bf);
    wt[idx] = f2b(v);
}

// bias -> bf16
__global__ void k_bias(const void* __restrict__ b, u16* __restrict__ dst,
                       const u32* __restrict__ flag)
{
    const u32 bf = *flag;
    const int i = threadIdx.x + blockIdx.x * 256;
    if (i < HIDDEN) dst[i] = f2b(load_in(b, i, bf));
}

__device__ __forceinline__ void acc_row(float* acc, const uint4 v, float s) {
    acc[0] += s * b2f(v.x & 0xffffu); acc[1] += s * b2f(v.x >> 16);
    acc[2] += s * b2f(v.y & 0xffffu); acc[3] += s * b2f(v.y >> 16);
    acc[4] += s * b2f(v.z & 0xffffu); acc[5] += s * b2f(v.z >> 16);
    acc[6] += s * b2f(v.w & 0xffffu); acc[7] += s * b2f(v.w >> 16);
}

// pre[b,:] = sum_j message[a2b[b2a[b],j],:] - message[b2revb[b],:]
__global__ void k_pre(const u16* __restrict__ message,
                      const int* __restrict__ a2b,
                      const int* __restrict__ b2a,
                      const int* __restrict__ b2revb,
                      u16* __restrict__ pre)
{
    const int b = blockIdx.x * 4 + (threadIdx.x >> 6);
    const int l = threadIdx.x & 63;
    const int a  = b2a[b];
    const int rb = b2revb[b];
    float acc[8] = {0.f, 0.f, 0.f, 0.f, 0.f, 0.f, 0.f, 0.f};
    acc_row(acc, *(const uint4*)(message + (size_t)rb * HIDDEN + l * 8), -1.f);
#pragma unroll
    for (int j = 0; j < MAX_NB; ++j) {
        const int nb = a2b[a * MAX_NB + j];
        acc_row(acc, *(const uint4*)(message + (size_t)nb * HIDDEN + l * 8), 1.f);
    }
    uint4 o;
    o.x = pack2(acc[0], acc[1]); o.y = pack2(acc[2], acc[3]);
    o.z = pack2(acc[4], acc[5]); o.w = pack2(acc[6], acc[7]);
    *(uint4*)(pre + (size_t)b * HIDDEN + l * 8) = o;
}

// ain[a, 0:512] = sum_j message[a2b[a,j],:]  (direct into GEMM A-layout)
__global__ void k_amsg(const u16* __restrict__ message,
                       const int* __restrict__ a2b,
                       u16* __restrict__ ain)
{
    const int a = blockIdx.x * 4 + (threadIdx.x >> 6);
    const int l = threadIdx.x & 63;
    float acc[8] = {0.f, 0.f, 0.f, 0.f, 0.f, 0.f, 0.f, 0.f};
#pragma unroll
    for (int j = 0; j < MAX_NB; ++j) {
        const int nb = a2b[a * MAX_NB + j];
        acc_row(acc, *(const uint4*)(message + (size_t)nb * HIDDEN + l * 8), 1.f);
    }
    uint4 o;
    o.x = pack2(acc[0], acc[1]); o.y = pack2(acc[2], acc[3]);
    o.z = pack2(acc[4], acc[5]); o.w = pack2(acc[6], acc[7]);
    *(uint4*)(ain + (size_t)a * KC + l * 8) = o;   // 16B-aligned: a*1344 + l*16
}

// ain[a, 512:645] = f_atoms[a,:] (converted), [645:672] = 0
__global__ void k_atomfill(const void* __restrict__ f_atoms,
                           u16* __restrict__ ain,
                           const u32* __restrict__ flag)
{
    const u32 bf = *flag;
    const int idx = blockIdx.x * 256 + threadIdx.x;
    if (idx >= N_ATOMS * (KC - HIDDEN)) return;
    const int a = idx / (KC - HIDDEN), c = idx - a * (KC - HIDDEN);
    u16 v = 0;
    if (c < ATOM_FDIM) v = f2b(load_in(f_atoms, (size_t)a * ATOM_FDIM + c, bf));
    ain[(size_t)a * KC + HIDDEN + c] = v;
}

// per-mol mean over sorted mol_ids; output dtype per flag
__global__ void k_mean(const u16* __restrict__ ah,
                       const int* __restrict__ mol_ids,
                       void* __restrict__ out,
                       const u32* __restrict__ flag)
{
    const u32 bf = *flag;
    const int m = blockIdx.x, t = threadIdx.x;
    int lo = 0, hi = N_ATOMS;
    while (lo < hi) { const int mid = (lo + hi) >> 1; if (mol_ids[mid] < m) lo = mid + 1; else hi = mid; }
    const int start = lo;
    hi = N_ATOMS;
    while (lo < hi) { const int mid = (lo + hi) >> 1; if (mol_ids[mid] <= m) lo = mid + 1; else hi = mid; }
    const int end = lo;
    float x = 0.f, y = 0.f;
    for (int a = start; a < end; ++a) {
        const u32 p = *(const u32*)(ah + (size_t)a * HIDDEN + t * 2);
        x += b2f(p & 0xffffu); y += b2f(p >> 16);
    }
    const float inv = (end > start) ? 1.f / (float)(end - start) : 0.f;
    x *= inv; y *= inv;
    if (bf) {
        *(u32*)((u16*)out + (size_t)m * HIDDEN + t * 2) = pack2(x, y);
    } else {
        float* o = (float*)out + (size_t)m * HIDDEN + t * 2;
        o[0] = x; o[1] = y;
    }
}

extern "C" void kernel_launch(void* const* d_in, const int* in_sizes, int n_in,
                              void* d_out, int out_size, void* d_ws, size_t ws_size,
                              hipStream_t stream)
{
    const void* f_atoms = d_in[0];
    const void* f_bonds = d_in[1];
    const int* a2b     = (const int*)d_in[2];
    const int* b2a     = (const int*)d_in[3];
    const int* b2revb  = (const int*)d_in[4];
    const int* mol_ids = (const int*)d_in[5];
    const void* W_i = d_in[6];
    const void* W_h = d_in[7];
    const void* W_o = d_in[8];
    const void* b_o = d_in[9];

    char* ws = (char*)d_ws;
    size_t off = 0;
    auto alloc = [&](size_t bytes) -> char* {
        char* p = ws + off;
        off += (bytes + 255) & ~(size_t)255;
        return p;
    };
    u32* flag     = (u32*)alloc(256);
    u16* biasB    = (u16*)alloc((size_t)HIDDEN * 2);
    u16* WcT      = (u16*)alloc((size_t)512 * KC * 2);         //  0.69 MB
    u16* WoT      = (u16*)alloc((size_t)512 * KC * 2);         //  0.69 MB
    u16* fbpad    = (u16*)alloc((size_t)N_BONDS * KB_PAD * 2); // 32.0 MB
    u16* pre      = (u16*)alloc((size_t)N_BONDS * HIDDEN * 2); //102.4 MB
    u16* message  = (u16*)alloc((size_t)N_BONDS * HIDDEN * 2); //102.4 MB
    // total ~238.2 MB. Aliases (lifetimes disjoint):
    u16* ain = pre;       // [50000, 672] = [amsg | f_atoms | 0], 67.2 MB (pre dead)
    u16* ah  = message;   // atom_hiddens [50000,512] (message dead after k_amsg)

    k_detect<<<dim3(1), 64, 0, stream>>>(f_bonds, flag);
    k_wcT<<<dim3((512 * KC + 255) / 256), 256, 0, stream>>>(W_i, W_h, WcT, flag);
    k_woT<<<dim3((512 * KC + 255) / 256), 256, 0, stream>>>(W_o, WoT, flag);
    k_bias<<<dim3(2), 256, 0, stream>>>(b_o, biasB, flag);
    k_pad_bonds<<<dim3((N_BONDS * KB_PAD + 255) / 256), 256, 0, stream>>>(f_bonds, fbpad, flag);

    const dim3 gB(4, (N_BONDS + 127) / 128);   // N-tiles fast: A-slab reuse
    // message = relu(f_bonds @ W_i)
    gemm_bt<1, 0><<<gB, 256, 0, stream>>>(fbpad, KB_PAD, pre, WcT, KC, nullptr,
                                          message, N_BONDS, KB_PAD);
    for (int d = 0; d < DEPTH - 1; ++d) {
        k_pre<<<dim3(N_BONDS / 4), 256, 0, stream>>>(message, a2b, b2a, b2revb, pre);
        // message = relu([fb | pre] @ [Wi ; Wh]) = relu(inp + pre @ W_h)
        gemm_bt<1, 0><<<gB, 256, 0, stream>>>(fbpad, KB_PAD, pre, WcT, KC, nullptr,
                                              message, N_BONDS, KC);
    }
    k_amsg<<<dim3(N_ATOMS / 4), 256, 0, stream>>>(message, a2b, ain);
    k_atomfill<<<dim3((N_ATOMS * (KC - HIDDEN) + 255) / 256), 256, 0, stream>>>(f_atoms, ain, flag);
    // atom_hiddens = relu(ain @ WoT + b_o)
    gemm_bt<0, 1><<<dim3(4, (N_ATOMS + 127) / 128), 256, 0, stream>>>(
        ain, KC, nullptr, WoT, KC, biasB, ah, N_ATOMS, KC);
    k_mean<<<dim3(N_MOLS), 256, 0, stream>>>(ah, mol_ids, d_out, flag);
}

// Round 5
// 1154.937 us; speedup vs baseline: 1.1344x; 1.0813x over previous
//
#include <hip/hip_runtime.h>

typedef unsigned int u32;
typedef unsigned short u16;

constexpr int N_ATOMS   = 50000;
constexpr int N_BONDS   = 100000;
constexpr int MAX_NB    = 6;
constexpr int ATOM_FDIM = 133;
constexpr int BOND_FDIM = 147;
constexpr int HIDDEN    = 512;
constexpr int DEPTH     = 5;
constexpr int N_MOLS    = 2048;
constexpr int KB_PAD    = 160;   // f_bonds K padded to mult of 32
constexpr int KC        = 672;   // combined K: 160 (Wi) + 512 (Wh); also 512+133 pad

typedef short bf16x8 __attribute__((ext_vector_type(8)));
typedef float f32x4  __attribute__((ext_vector_type(4)));

__device__ __forceinline__ float b2f(u32 u) {
    u <<= 16; float f; __builtin_memcpy(&f, &u, 4); return f;
}
__device__ __forceinline__ u16 f2b(float f) {
    u32 u; __builtin_memcpy(&u, &f, 4);
    u = (u + 0x7fffu + ((u >> 16) & 1u)) >> 16;
    return (u16)u;
}
__device__ __forceinline__ u32 pack2(float x, float y) {
    return (u32)f2b(x) | ((u32)f2b(y) << 16);
}
// read input element i as float; bf=1 -> data is bf16, bf=0 -> data is f32
__device__ __forceinline__ float load_in(const void* p, size_t i, u32 bf) {
    return bf ? b2f((u32)((const u16*)p)[i]) : ((const float*)p)[i];
}

// detect input dtype from f_bonds bit patterns (N(0,1) data)
__global__ void k_detect(const void* fb, u32* flag) {
    if (threadIdx.x == 0 && blockIdx.x == 0) {
        const u16* p = (const u16*)fb;
        int cnt = 0;
        for (int i = 0; i < 64; ++i) {
            const u32 e = (p[i] >> 7) & 0xFF;
            if (e >= 110 && e <= 140) ++cnt;
        }
        *flag = (cnt >= 52) ? 1u : 0u;   // 1 = inputs are bf16
    }
}

// ---------------------------------------------------------------------------
// MFMA GEMM: C[M,512] = A[M,K] @ B[K,512], B transposed (BT[512,ldb]), bf16.
// 128x128 tile, BK=32, 256 threads (4 waves 2x2), global_load_lds staging.
// LDS XOR swizzle: chunk (row r, pos p) holds global k-group p^((r>>1)&3)
//   -> fragment reads are 2-way-conflict-free (2-way is free per m136).
// XCD-aligned 1D grid: g -> m=( g>>5 )*8+(g&7), n=(g>>3)&3 so the 4 N-tile
//   blocks sharing an A-slab land on the same XCD (assuming XCD = bid%8).
// SPLIT: A cols [0,160) from A (lda ldaA), [160,K) from A2 (lda 512).
// MODE 0: out = relu(C)      MODE 1: out = relu(C + bias[col])
// ---------------------------------------------------------------------------
template <int SPLIT, int MODE>
__global__ void gemm_bt(const u16* __restrict__ A, int ldaA,
                        const u16* __restrict__ A2,
                        const u16* __restrict__ BT, int ldb,
                        const u16* __restrict__ bias,
                        u16* __restrict__ out,
                        int M, int K)
{
    __shared__ u16 As[128 * 32];
    __shared__ u16 Bs[128 * 32];
    const int g    = blockIdx.x;
    const int mt   = (g >> 5) * 8 + (g & 7);
    const int nt   = (g >> 3) & 3;
    const int bm0  = mt * 128;
    if (bm0 >= M) return;                  // pad-block early exit (whole block)
    const int bn0  = nt * 128;
    const int t    = threadIdx.x;
    const int w    = t >> 6;
    const int l    = t & 63;
    const int quad = l >> 4;
    const int lr   = l & 15;
    const int wr   = (w >> 1) * 64;
    const int wc   = (w & 1) * 64;

    f32x4 acc[4][4];
#pragma unroll
    for (int i = 0; i < 4; ++i)
#pragma unroll
        for (int j = 0; j < 4; ++j) acc[i][j] = (f32x4){0.f, 0.f, 0.f, 0.f};

    const int kt_n = K >> 5;
    for (int kt = 0; kt < kt_n; ++kt) {
        const int k0 = kt << 5;
        const u16* srcA;
        int lda, kcol;
        if (SPLIT && kt >= 5) { srcA = A2; lda = HIDDEN; kcol = k0 - KB_PAD; }
        else                  { srcA = A;  lda = ldaA;   kcol = k0; }
        __syncthreads();   // previous tile's LDS reads done before overwrite
        // chunk c (16 B): row r=c>>2, pos c&3; LDS linear = c*16 B.
        // Source k-group is XOR-swizzled: kg = (c&3) ^ ((r>>1)&3).
#pragma unroll
        for (int j = 0; j < 2; ++j) {
            const int cj = w + j * 4;          // wave-uniform chunk group 0..7
            const int c  = cj * 64 + l;
            const int r  = c >> 2;
            const int kg = (c & 3) ^ ((r >> 1) & 3);
            int rowA = bm0 + r; if (rowA >= M) rowA = M - 1;
            const u16* ga = srcA + (size_t)rowA * lda + kcol + kg * 8;
            __builtin_amdgcn_global_load_lds(
                (const __attribute__((address_space(1))) void*)ga,
                (__attribute__((address_space(3))) void*)(As + cj * 512),
                16, 0, 0);
            const int rowB = bn0 + r;          // always < 512
            const u16* gb = BT + (size_t)rowB * ldb + k0 + kg * 8;
            __builtin_amdgcn_global_load_lds(
                (const __attribute__((address_space(1))) void*)gb,
                (__attribute__((address_space(3))) void*)(Bs + cj * 512),
                16, 0, 0);
        }
        __syncthreads();

        bf16x8 af[4], bfr[4];
#pragma unroll
        for (int i = 0; i < 4; ++i) {
            const int ra = wr + i * 16 + lr;
            const int rb = wc + i * 16 + lr;
            af[i]  = *(const bf16x8*)(As + ra * 32 + (quad ^ ((ra >> 1) & 3)) * 8);
            bfr[i] = *(const bf16x8*)(Bs + rb * 32 + (quad ^ ((rb >> 1) & 3)) * 8);
        }
#pragma unroll
        for (int i = 0; i < 4; ++i)
#pragma unroll
            for (int j = 0; j < 4; ++j)
                acc[i][j] = __builtin_amdgcn_mfma_f32_16x16x32_bf16(
                    af[i], bfr[j], acc[i][j], 0, 0, 0);
    }

    // epilogue: D row=(quad*4+reg), col=lr within each 16x16 subtile
#pragma unroll
    for (int i = 0; i < 4; ++i) {
        const int row0 = bm0 + wr + i * 16 + quad * 4;
#pragma unroll
        for (int j = 0; j < 4; ++j) {
            const int col = bn0 + wc + j * 16 + lr;
#pragma unroll
            for (int r = 0; r < 4; ++r) {
                const int row = row0 + r;
                if (row < M) {
                    float v = acc[i][j][r];
                    if (MODE == 1) v += b2f((u32)bias[col]);
                    out[(size_t)row * HIDDEN + col] = f2b(v > 0.f ? v : 0.f);
                }
            }
        }
    }
}

// grid size helper: 4 N-tiles x M-tiles padded to mult of 8
static inline int gemm_grid(int M) { return (((M + 127) / 128 + 7) & ~7) * 4; }

// pad+convert f_bonds [N_BONDS,147] -> bf16 [N_BONDS,160]
__global__ void k_pad_bonds(const void* __restrict__ src,
                            u16* __restrict__ dst,
                            const u32* __restrict__ flag)
{
    const u32 bf = *flag;
    const int idx = blockIdx.x * 256 + threadIdx.x;
    if (idx >= N_BONDS * KB_PAD) return;
    const int b = idx / KB_PAD, k = idx - b * KB_PAD;
    dst[idx] = (k < BOND_FDIM) ? f2b(load_in(src, (size_t)b * BOND_FDIM + k, bf))
                               : (u16)0;
}

// WcT[n*672 + k] = k<147 ? W_i[k,n] : k<160 ? 0 : W_h[k-160,n]   (bf16)
__global__ void k_wcT(const void* __restrict__ wi,
                      const void* __restrict__ wh,
                      u16* __restrict__ wt,
                      const u32* __restrict__ flag)
{
    const u32 bf = *flag;
    const int idx = blockIdx.x * 256 + threadIdx.x;
    if (idx >= 512 * KC) return;
    const int n = idx / KC, k = idx - n * KC;
    float v = 0.f;
    if (k < BOND_FDIM)    v = load_in(wi, (size_t)k * HIDDEN + n, bf);
    else if (k >= KB_PAD) v = load_in(wh, (size_t)(k - KB_PAD) * HIDDEN + n, bf);
    wt[idx] = f2b(v);
}

// W_o rows permuted to match ain = [amsg(512) | f_atoms(133) | pad(27)]:
// WoT[n*672+k] = k<512 ? W_o[133+k, n] : k<645 ? W_o[k-512, n] : 0
__global__ void k_woT(const void* __restrict__ wo,
                      u16* __restrict__ wt,
                      const u32* __restrict__ flag)
{
    const u32 bf = *flag;
    const int idx = blockIdx.x * 256 + threadIdx.x;
    if (idx >= 512 * KC) return;
    const int n = idx / KC, k = idx - n * KC;
    float v = 0.f;
    if (k < HIDDEN)                  v = load_in(wo, (size_t)(ATOM_FDIM + k) * HIDDEN + n, bf);
    else if (k < HIDDEN + ATOM_FDIM) v = load_in(wo, (size_t)(k - HIDDEN) * HIDDEN + n, bf);
    wt[idx] = f2b(v);
}

// bias -> bf16
__global__ void k_bias(const void* __restrict__ b, u16* __restrict__ dst,
                       const u32* __restrict__ flag)
{
    const u32 bf = *flag;
    const int i = threadIdx.x + blockIdx.x * 256;
    if (i < HIDDEN) dst[i] = f2b(load_in(b, i, bf));
}

__device__ __forceinline__ void acc_row(float* acc, const uint4 v, float s) {
    acc[0] += s * b2f(v.x & 0xffffu); acc[1] += s * b2f(v.x >> 16);
    acc[2] += s * b2f(v.y & 0xffffu); acc[3] += s * b2f(v.y >> 16);
    acc[4] += s * b2f(v.z & 0xffffu); acc[5] += s * b2f(v.z >> 16);
    acc[6] += s * b2f(v.w & 0xffffu); acc[7] += s * b2f(v.w >> 16);
}

// pre[b,:] = sum_j message[a2b[b2a[b],j],:] - message[b2revb[b],:]
__global__ void k_pre(const u16* __restrict__ message,
                      const int* __restrict__ a2b,
                      const int* __restrict__ b2a,
                      const int* __restrict__ b2revb,
                      u16* __restrict__ pre)
{
    const int b = blockIdx.x * 4 + (threadIdx.x >> 6);
    const int l = threadIdx.x & 63;
    const int a  = b2a[b];
    const int rb = b2revb[b];
    float acc[8] = {0.f, 0.f, 0.f, 0.f, 0.f, 0.f, 0.f, 0.f};
    acc_row(acc, *(const uint4*)(message + (size_t)rb * HIDDEN + l * 8), -1.f);
#pragma unroll
    for (int j = 0; j < MAX_NB; ++j) {
        const int nb = a2b[a * MAX_NB + j];
        acc_row(acc, *(const uint4*)(message + (size_t)nb * HIDDEN + l * 8), 1.f);
    }
    uint4 o;
    o.x = pack2(acc[0], acc[1]); o.y = pack2(acc[2], acc[3]);
    o.z = pack2(acc[4], acc[5]); o.w = pack2(acc[6], acc[7]);
    *(uint4*)(pre + (size_t)b * HIDDEN + l * 8) = o;
}

// ain[a, 0:512] = sum_j message[a2b[a,j],:]  (direct into GEMM A-layout)
__global__ void k_amsg(const u16* __restrict__ message,
                       const int* __restrict__ a2b,
                       u16* __restrict__ ain)
{
    const int a = blockIdx.x * 4 + (threadIdx.x >> 6);
    const int l = threadIdx.x & 63;
    float acc[8] = {0.f, 0.f, 0.f, 0.f, 0.f, 0.f, 0.f, 0.f};
#pragma unroll
    for (int j = 0; j < MAX_NB; ++j) {
        const int nb = a2b[a * MAX_NB + j];
        acc_row(acc, *(const uint4*)(message + (size_t)nb * HIDDEN + l * 8), 1.f);
    }
    uint4 o;
    o.x = pack2(acc[0], acc[1]); o.y = pack2(acc[2], acc[3]);
    o.z = pack2(acc[4], acc[5]); o.w = pack2(acc[6], acc[7]);
    *(uint4*)(ain + (size_t)a * KC + l * 8) = o;   // 16B-aligned: a*1344 + l*16
}

// ain[a, 512:645] = f_atoms[a,:] (converted), [645:672] = 0
__global__ void k_atomfill(const void* __restrict__ f_atoms,
                           u16* __restrict__ ain,
                           const u32* __restrict__ flag)
{
    const u32 bf = *flag;
    const int idx = blockIdx.x * 256 + threadIdx.x;
    if (idx >= N_ATOMS * (KC - HIDDEN)) return;
    const int a = idx / (KC - HIDDEN), c = idx - a * (KC - HIDDEN);
    u16 v = 0;
    if (c < ATOM_FDIM) v = f2b(load_in(f_atoms, (size_t)a * ATOM_FDIM + c, bf));
    ain[(size_t)a * KC + HIDDEN + c] = v;
}

// per-mol mean over sorted mol_ids; output dtype per flag
__global__ void k_mean(const u16* __restrict__ ah,
                       const int* __restrict__ mol_ids,
                       void* __restrict__ out,
                       const u32* __restrict__ flag)
{
    const u32 bf = *flag;
    const int m = blockIdx.x, t = threadIdx.x;
    int lo = 0, hi = N_ATOMS;
    while (lo < hi) { const int mid = (lo + hi) >> 1; if (mol_ids[mid] < m) lo = mid + 1; else hi = mid; }
    const int start = lo;
    hi = N_ATOMS;
    while (lo < hi) { const int mid = (lo + hi) >> 1; if (mol_ids[mid] <= m) lo = mid + 1; else hi = mid; }
    const int end = lo;
    float x = 0.f, y = 0.f;
    for (int a = start; a < end; ++a) {
        const u32 p = *(const u32*)(ah + (size_t)a * HIDDEN + t * 2);
        x += b2f(p & 0xffffu); y += b2f(p >> 16);
    }
    const float inv = (end > start) ? 1.f / (float)(end - start) : 0.f;
    x *= inv; y *= inv;
    if (bf) {
        *(u32*)((u16*)out + (size_t)m * HIDDEN + t * 2) = pack2(x, y);
    } else {
        float* o = (float*)out + (size_t)m * HIDDEN + t * 2;
        o[0] = x; o[1] = y;
    }
}

extern "C" void kernel_launch(void* const* d_in, const int* in_sizes, int n_in,
                              void* d_out, int out_size, void* d_ws, size_t ws_size,
                              hipStream_t stream)
{
    const void* f_atoms = d_in[0];
    const void* f_bonds = d_in[1];
    const int* a2b     = (const int*)d_in[2];
    const int* b2a     = (const int*)d_in[3];
    const int* b2revb  = (const int*)d_in[4];
    const int* mol_ids = (const int*)d_in[5];
    const void* W_i = d_in[6];
    const void* W_h = d_in[7];
    const void* W_o = d_in[8];
    const void* b_o = d_in[9];

    char* ws = (char*)d_ws;
    size_t off = 0;
    auto alloc = [&](size_t bytes) -> char* {
        char* p = ws + off;
        off += (bytes + 255) & ~(size_t)255;
        return p;
    };
    u32* flag     = (u32*)alloc(256);
    u16* biasB    = (u16*)alloc((size_t)HIDDEN * 2);
    u16* WcT      = (u16*)alloc((size_t)512 * KC * 2);         //  0.69 MB
    u16* WoT      = (u16*)alloc((size_t)512 * KC * 2);         //  0.69 MB
    u16* fbpad    = (u16*)alloc((size_t)N_BONDS * KB_PAD * 2); // 32.0 MB
    u16* pre      = (u16*)alloc((size_t)N_BONDS * HIDDEN * 2); //102.4 MB
    u16* message  = (u16*)alloc((size_t)N_BONDS * HIDDEN * 2); //102.4 MB
    // total ~238.2 MB. Aliases (lifetimes disjoint):
    u16* ain = pre;       // [50000, 672] = [amsg | f_atoms | 0], 67.2 MB (pre dead)
    u16* ah  = message;   // atom_hiddens [50000,512] (message dead after k_amsg)

    k_detect<<<dim3(1), 64, 0, stream>>>(f_bonds, flag);
    k_wcT<<<dim3((512 * KC + 255) / 256), 256, 0, stream>>>(W_i, W_h, WcT, flag);
    k_woT<<<dim3((512 * KC + 255) / 256), 256, 0, stream>>>(W_o, WoT, flag);
    k_bias<<<dim3(2), 256, 0, stream>>>(b_o, biasB, flag);
    k_pad_bonds<<<dim3((N_BONDS * KB_PAD + 255) / 256), 256, 0, stream>>>(f_bonds, fbpad, flag);

    const dim3 gB(gemm_grid(N_BONDS));
    // message = relu(f_bonds @ W_i)
    gemm_bt<1, 0><<<gB, 256, 0, stream>>>(fbpad, KB_PAD, pre, WcT, KC, nullptr,
                                          message, N_BONDS, KB_PAD);
    for (int d = 0; d < DEPTH - 1; ++d) {
        k_pre<<<dim3(N_BONDS / 4), 256, 0, stream>>>(message, a2b, b2a, b2revb, pre);
        // message = relu([fb | pre] @ [Wi ; Wh]) = relu(inp + pre @ W_h)
        gemm_bt<1, 0><<<gB, 256, 0, stream>>>(fbpad, KB_PAD, pre, WcT, KC, nullptr,
                                              message, N_BONDS, KC);
    }
    k_amsg<<<dim3(N_ATOMS / 4), 256, 0, stream>>>(message, a2b, ain);
    k_atomfill<<<dim3((N_ATOMS * (KC - HIDDEN) + 255) / 256), 256, 0, stream>>>(f_atoms, ain, flag);
    // atom_hiddens = relu(ain @ WoT + b_o)
    gemm_bt<0, 1><<<dim3(gemm_grid(N_ATOMS)), 256, 0, stream>>>(
        ain, KC, nullptr, WoT, KC, biasB, ah, N_ATOMS, KC);
    k_mean<<<dim3(N_MOLS), 256, 0, stream>>>(ah, mol_ids, d_out, flag);
}

// Round 6
// 1054.384 us; speedup vs baseline: 1.2425x; 1.0954x over previous
//
#include <hip/hip_runtime.h>

typedef unsigned int u32;
typedef unsigned short u16;

constexpr int N_ATOMS   = 50000;
constexpr int N_BONDS   = 100000;
constexpr int MAX_NB    = 6;
constexpr int ATOM_FDIM = 133;
constexpr int BOND_FDIM = 147;
constexpr int HIDDEN    = 512;
constexpr int DEPTH     = 5;
constexpr int N_MOLS    = 2048;
constexpr int KB_PAD    = 160;   // f_bonds K padded to mult of 32
constexpr int KC        = 672;   // combined K: 160 (Wi) + 512 (Wh); also 512+133 pad

typedef short bf16x8 __attribute__((ext_vector_type(8)));
typedef float f32x4  __attribute__((ext_vector_type(4)));

__device__ __forceinline__ float b2f(u32 u) {
    u <<= 16; float f; __builtin_memcpy(&f, &u, 4); return f;
}
__device__ __forceinline__ u16 f2b(float f) {
    u32 u; __builtin_memcpy(&u, &f, 4);
    u = (u + 0x7fffu + ((u >> 16) & 1u)) >> 16;
    return (u16)u;
}
__device__ __forceinline__ u32 pack2(float x, float y) {
    return (u32)f2b(x) | ((u32)f2b(y) << 16);
}
// read input element i as float; bf=1 -> data is bf16, bf=0 -> data is f32
__device__ __forceinline__ float load_in(const void* p, size_t i, u32 bf) {
    return bf ? b2f((u32)((const u16*)p)[i]) : ((const float*)p)[i];
}

// detect input dtype from f_bonds bit patterns (N(0,1) data)
__global__ void k_detect(const void* fb, u32* flag) {
    if (threadIdx.x == 0 && blockIdx.x == 0) {
        const u16* p = (const u16*)fb;
        int cnt = 0;
        for (int i = 0; i < 64; ++i) {
            const u32 e = (p[i] >> 7) & 0xFF;
            if (e >= 110 && e <= 140) ++cnt;
        }
        *flag = (cnt >= 52) ? 1u : 0u;   // 1 = inputs are bf16
    }
}

// ---------------------------------------------------------------------------
// MFMA GEMM (unchanged from R5): C[M,512] = A[M,K] @ BT^T, 128x128 tile,
// BK=32, global_load_lds staging, XOR bank swizzle, XCD-aligned 1D grid.
// ---------------------------------------------------------------------------
template <int SPLIT, int MODE>
__global__ void gemm_bt(const u16* __restrict__ A, int ldaA,
                        const u16* __restrict__ A2,
                        const u16* __restrict__ BT, int ldb,
                        const u16* __restrict__ bias,
                        u16* __restrict__ out,
                        int M, int K)
{
    __shared__ u16 As[128 * 32];
    __shared__ u16 Bs[128 * 32];
    const int g    = blockIdx.x;
    const int mt   = (g >> 5) * 8 + (g & 7);
    const int nt   = (g >> 3) & 3;
    const int bm0  = mt * 128;
    if (bm0 >= M) return;
    const int bn0  = nt * 128;
    const int t    = threadIdx.x;
    const int w    = t >> 6;
    const int l    = t & 63;
    const int quad = l >> 4;
    const int lr   = l & 15;
    const int wr   = (w >> 1) * 64;
    const int wc   = (w & 1) * 64;

    f32x4 acc[4][4];
#pragma unroll
    for (int i = 0; i < 4; ++i)
#pragma unroll
        for (int j = 0; j < 4; ++j) acc[i][j] = (f32x4){0.f, 0.f, 0.f, 0.f};

    const int kt_n = K >> 5;
    for (int kt = 0; kt < kt_n; ++kt) {
        const int k0 = kt << 5;
        const u16* srcA;
        int lda, kcol;
        if (SPLIT && kt >= 5) { srcA = A2; lda = HIDDEN; kcol = k0 - KB_PAD; }
        else                  { srcA = A;  lda = ldaA;   kcol = k0; }
        __syncthreads();
#pragma unroll
        for (int j = 0; j < 2; ++j) {
            const int cj = w + j * 4;
            const int c  = cj * 64 + l;
            const int r  = c >> 2;
            const int kg = (c & 3) ^ ((r >> 1) & 3);
            int rowA = bm0 + r; if (rowA >= M) rowA = M - 1;
            const u16* ga = srcA + (size_t)rowA * lda + kcol + kg * 8;
            __builtin_amdgcn_global_load_lds(
                (const __attribute__((address_space(1))) void*)ga,
                (__attribute__((address_space(3))) void*)(As + cj * 512),
                16, 0, 0);
            const int rowB = bn0 + r;
            const u16* gb = BT + (size_t)rowB * ldb + k0 + kg * 8;
            __builtin_amdgcn_global_load_lds(
                (const __attribute__((address_space(1))) void*)gb,
                (__attribute__((address_space(3))) void*)(Bs + cj * 512),
                16, 0, 0);
        }
        __syncthreads();

        bf16x8 af[4], bfr[4];
#pragma unroll
        for (int i = 0; i < 4; ++i) {
            const int ra = wr + i * 16 + lr;
            const int rb = wc + i * 16 + lr;
            af[i]  = *(const bf16x8*)(As + ra * 32 + (quad ^ ((ra >> 1) & 3)) * 8);
            bfr[i] = *(const bf16x8*)(Bs + rb * 32 + (quad ^ ((rb >> 1) & 3)) * 8);
        }
#pragma unroll
        for (int i = 0; i < 4; ++i)
#pragma unroll
            for (int j = 0; j < 4; ++j)
                acc[i][j] = __builtin_amdgcn_mfma_f32_16x16x32_bf16(
                    af[i], bfr[j], acc[i][j], 0, 0, 0);
    }

#pragma unroll
    for (int i = 0; i < 4; ++i) {
        const int row0 = bm0 + wr + i * 16 + quad * 4;
#pragma unroll
        for (int j = 0; j < 4; ++j) {
            const int col = bn0 + wc + j * 16 + lr;
#pragma unroll
            for (int r = 0; r < 4; ++r) {
                const int row = row0 + r;
                if (row < M) {
                    float v = acc[i][j][r];
                    if (MODE == 1) v += b2f((u32)bias[col]);
                    out[(size_t)row * HIDDEN + col] = f2b(v > 0.f ? v : 0.f);
                }
            }
        }
    }
}

static inline int gemm_grid(int M) { return (((M + 127) / 128 + 7) & ~7) * 4; }

// pad+convert f_bonds [N_BONDS,147] -> bf16 [N_BONDS,160]
__global__ void k_pad_bonds(const void* __restrict__ src,
                            u16* __restrict__ dst,
                            const u32* __restrict__ flag)
{
    const u32 bf = *flag;
    const int idx = blockIdx.x * 256 + threadIdx.x;
    if (idx >= N_BONDS * KB_PAD) return;
    const int b = idx / KB_PAD, k = idx - b * KB_PAD;
    dst[idx] = (k < BOND_FDIM) ? f2b(load_in(src, (size_t)b * BOND_FDIM + k, bf))
                               : (u16)0;
}

// WcT[n*672 + k] = k<147 ? W_i[k,n] : k<160 ? 0 : W_h[k-160,n]   (bf16)
__global__ void k_wcT(const void* __restrict__ wi,
                      const void* __restrict__ wh,
                      u16* __restrict__ wt,
                      const u32* __restrict__ flag)
{
    const u32 bf = *flag;
    const int idx = blockIdx.x * 256 + threadIdx.x;
    if (idx >= 512 * KC) return;
    const int n = idx / KC, k = idx - n * KC;
    float v = 0.f;
    if (k < BOND_FDIM)    v = load_in(wi, (size_t)k * HIDDEN + n, bf);
    else if (k >= KB_PAD) v = load_in(wh, (size_t)(k - KB_PAD) * HIDDEN + n, bf);
    wt[idx] = f2b(v);
}

// W_o rows permuted to match ain = [amsg(512) | f_atoms(133) | pad(27)]
__global__ void k_woT(const void* __restrict__ wo,
                      u16* __restrict__ wt,
                      const u32* __restrict__ flag)
{
    const u32 bf = *flag;
    const int idx = blockIdx.x * 256 + threadIdx.x;
    if (idx >= 512 * KC) return;
    const int n = idx / KC, k = idx - n * KC;
    float v = 0.f;
    if (k < HIDDEN)                  v = load_in(wo, (size_t)(ATOM_FDIM + k) * HIDDEN + n, bf);
    else if (k < HIDDEN + ATOM_FDIM) v = load_in(wo, (size_t)(k - HIDDEN) * HIDDEN + n, bf);
    wt[idx] = f2b(v);
}

// bias -> bf16
__global__ void k_bias(const void* __restrict__ b, u16* __restrict__ dst,
                       const u32* __restrict__ flag)
{
    const u32 bf = *flag;
    const int i = threadIdx.x + blockIdx.x * 256;
    if (i < HIDDEN) dst[i] = f2b(load_in(b, i, bf));
}

// ---------- CSR build: atom -> list of out-bonds (bonds with b2a[b]==a) ----
__global__ void k_zero(u32* p, int n) {
    const int i = blockIdx.x * 256 + threadIdx.x;
    if (i < n) p[i] = 0;
}
__global__ void k_count(const int* __restrict__ b2a, u32* __restrict__ cnt) {
    const int b = blockIdx.x * 256 + threadIdx.x;
    if (b < N_BONDS) atomicAdd(&cnt[b2a[b]], 1u);
}
// single-block exclusive scan of cnt[50000] -> off[50001]
__global__ void k_scan(const u32* __restrict__ cnt, u32* __restrict__ off) {
    __shared__ u32 part[1024];
    __shared__ u32 carry;
    const int t = threadIdx.x;
    constexpr int CH = (N_ATOMS + 1023) / 1024;   // 49
    u32 local[CH];
    u32 s = 0;
    for (int j = 0; j < CH; ++j) {
        const int i = t * CH + j;
        local[j] = s;
        if (i < N_ATOMS) s += cnt[i];
    }
    part[t] = s;
    __syncthreads();
    if (t == 0) {
        u32 run = 0;
        for (int i = 0; i < 1024; ++i) { const u32 v = part[i]; part[i] = run; run += v; }
        carry = run;   // total (== N_BONDS)
    }
    __syncthreads();
    const u32 base = part[t];
    for (int j = 0; j < CH; ++j) {
        const int i = t * CH + j;
        if (i < N_ATOMS) off[i] = base + local[j];
    }
    if (t == 0) off[N_ATOMS] = carry;
}
__global__ void k_scatter(const int* __restrict__ b2a,
                          u32* __restrict__ pos, u32* __restrict__ csr) {
    const int b = blockIdx.x * 256 + threadIdx.x;
    if (b < N_BONDS) {
        const u32 p = atomicAdd(&pos[b2a[b]], 1u);
        csr[p] = (u32)b;
    }
}

__device__ __forceinline__ void acc_row(float* acc, const uint4 v, float s) {
    acc[0] += s * b2f(v.x & 0xffffu); acc[1] += s * b2f(v.x >> 16);
    acc[2] += s * b2f(v.y & 0xffffu); acc[3] += s * b2f(v.y >> 16);
    acc[4] += s * b2f(v.z & 0xffffu); acc[5] += s * b2f(v.z >> 16);
    acc[6] += s * b2f(v.w & 0xffffu); acc[7] += s * b2f(v.w >> 16);
}

// atom-grouped pre: wave per atom computes amsg once, reuses for its out-bonds.
// pre[b,:] = amsg[b2a[b],:] - message[b2revb[b],:]  for b in csr[off[a]..off[a+1])
__global__ void k_pre_g(const u16* __restrict__ message,
                        const int* __restrict__ a2b,
                        const u32* __restrict__ csr,
                        const u32* __restrict__ off,
                        const int* __restrict__ b2revb,
                        u16* __restrict__ pre)
{
    const int a = blockIdx.x * 4 + (threadIdx.x >> 6);
    if (a >= N_ATOMS) return;
    const int l = threadIdx.x & 63;
    const int s = (int)off[a], e = (int)off[a + 1];
    if (s == e) return;
    float acc[8] = {0.f, 0.f, 0.f, 0.f, 0.f, 0.f, 0.f, 0.f};
#pragma unroll
    for (int j = 0; j < MAX_NB; ++j) {
        const int nb = a2b[a * MAX_NB + j];
        acc_row(acc, *(const uint4*)(message + (size_t)nb * HIDDEN + l * 8), 1.f);
    }
    for (int i = s; i < e; ++i) {
        const int b  = (int)csr[i];
        const int rb = b2revb[b];
        const uint4 vm = *(const uint4*)(message + (size_t)rb * HIDDEN + l * 8);
        uint4 o;
        o.x = pack2(acc[0] - b2f(vm.x & 0xffffu), acc[1] - b2f(vm.x >> 16));
        o.y = pack2(acc[2] - b2f(vm.y & 0xffffu), acc[3] - b2f(vm.y >> 16));
        o.z = pack2(acc[4] - b2f(vm.z & 0xffffu), acc[5] - b2f(vm.z >> 16));
        o.w = pack2(acc[6] - b2f(vm.w & 0xffffu), acc[7] - b2f(vm.w >> 16));
        *(uint4*)(pre + (size_t)b * HIDDEN + l * 8) = o;
    }
}

// ain[a, 0:512] = sum_j message[a2b[a,j],:]  (direct into GEMM A-layout)
__global__ void k_amsg(const u16* __restrict__ message,
                       const int* __restrict__ a2b,
                       u16* __restrict__ ain)
{
    const int a = blockIdx.x * 4 + (threadIdx.x >> 6);
    const int l = threadIdx.x & 63;
    float acc[8] = {0.f, 0.f, 0.f, 0.f, 0.f, 0.f, 0.f, 0.f};
#pragma unroll
    for (int j = 0; j < MAX_NB; ++j) {
        const int nb = a2b[a * MAX_NB + j];
        acc_row(acc, *(const uint4*)(message + (size_t)nb * HIDDEN + l * 8), 1.f);
    }
    uint4 o;
    o.x = pack2(acc[0], acc[1]); o.y = pack2(acc[2], acc[3]);
    o.z = pack2(acc[4], acc[5]); o.w = pack2(acc[6], acc[7]);
    *(uint4*)(ain + (size_t)a * KC + l * 8) = o;
}

// ain[a, 512:645] = f_atoms[a,:] (converted), [645:672] = 0
__global__ void k_atomfill(const void* __restrict__ f_atoms,
                           u16* __restrict__ ain,
                           const u32* __restrict__ flag)
{
    const u32 bf = *flag;
    const int idx = blockIdx.x * 256 + threadIdx.x;
    if (idx >= N_ATOMS * (KC - HIDDEN)) return;
    const int a = idx / (KC - HIDDEN), c = idx - a * (KC - HIDDEN);
    u16 v = 0;
    if (c < ATOM_FDIM) v = f2b(load_in(f_atoms, (size_t)a * ATOM_FDIM + c, bf));
    ain[(size_t)a * KC + HIDDEN + c] = v;
}

// per-mol mean over sorted mol_ids
__global__ void k_mean(const u16* __restrict__ ah,
                       const int* __restrict__ mol_ids,
                       void* __restrict__ out,
                       const u32* __restrict__ flag)
{
    const u32 bf = *flag;
    const int m = blockIdx.x, t = threadIdx.x;
    int lo = 0, hi = N_ATOMS;
    while (lo < hi) { const int mid = (lo + hi) >> 1; if (mol_ids[mid] < m) lo = mid + 1; else hi = mid; }
    const int start = lo;
    hi = N_ATOMS;
    while (lo < hi) { const int mid = (lo + hi) >> 1; if (mol_ids[mid] <= m) lo = mid + 1; else hi = mid; }
    const int end = lo;
    float x = 0.f, y = 0.f;
    for (int a = start; a < end; ++a) {
        const u32 p = *(const u32*)(ah + (size_t)a * HIDDEN + t * 2);
        x += b2f(p & 0xffffu); y += b2f(p >> 16);
    }
    const float inv = (end > start) ? 1.f / (float)(end - start) : 0.f;
    x *= inv; y *= inv;
    if (bf) {
        *(u32*)((u16*)out + (size_t)m * HIDDEN + t * 2) = pack2(x, y);
    } else {
        float* o = (float*)out + (size_t)m * HIDDEN + t * 2;
        o[0] = x; o[1] = y;
    }
}

extern "C" void kernel_launch(void* const* d_in, const int* in_sizes, int n_in,
                              void* d_out, int out_size, void* d_ws, size_t ws_size,
                              hipStream_t stream)
{
    const void* f_atoms = d_in[0];
    const void* f_bonds = d_in[1];
    const int* a2b     = (const int*)d_in[2];
    const int* b2a     = (const int*)d_in[3];
    const int* b2revb  = (const int*)d_in[4];
    const int* mol_ids = (const int*)d_in[5];
    const void* W_i = d_in[6];
    const void* W_h = d_in[7];
    const void* W_o = d_in[8];
    const void* b_o = d_in[9];

    char* ws = (char*)d_ws;
    size_t off_ = 0;
    auto alloc = [&](size_t bytes) -> char* {
        char* p = ws + off_;
        off_ += (bytes + 255) & ~(size_t)255;
        return p;
    };
    u32* flag     = (u32*)alloc(256);
    u16* biasB    = (u16*)alloc((size_t)HIDDEN * 2);
    u16* WcT      = (u16*)alloc((size_t)512 * KC * 2);
    u16* WoT      = (u16*)alloc((size_t)512 * KC * 2);
    u32* cnt      = (u32*)alloc((size_t)N_ATOMS * 4);        // 0.2 MB
    u32* offs     = (u32*)alloc((size_t)(N_ATOMS + 1) * 4);  // 0.2 MB
    u32* pos      = (u32*)alloc((size_t)N_ATOMS * 4);        // 0.2 MB
    u32* csr      = (u32*)alloc((size_t)N_BONDS * 4);        // 0.4 MB
    u16* fbpad    = (u16*)alloc((size_t)N_BONDS * KB_PAD * 2); // 32.0 MB
    u16* pre      = (u16*)alloc((size_t)N_BONDS * HIDDEN * 2); //102.4 MB
    u16* message  = (u16*)alloc((size_t)N_BONDS * HIDDEN * 2); //102.4 MB
    // ~239.5 MB total. Aliases (lifetimes disjoint):
    u16* ain = pre;       // [50000, 672] = [amsg | f_atoms | 0]
    u16* ah  = message;   // atom_hiddens [50000,512]

    k_detect<<<dim3(1), 64, 0, stream>>>(f_bonds, flag);
    k_wcT<<<dim3((512 * KC + 255) / 256), 256, 0, stream>>>(W_i, W_h, WcT, flag);
    k_woT<<<dim3((512 * KC + 255) / 256), 256, 0, stream>>>(W_o, WoT, flag);
    k_bias<<<dim3(2), 256, 0, stream>>>(b_o, biasB, flag);
    k_pad_bonds<<<dim3((N_BONDS * KB_PAD + 255) / 256), 256, 0, stream>>>(f_bonds, fbpad, flag);

    // CSR build (atom -> out-bonds)
    k_zero<<<dim3((N_ATOMS + 255) / 256), 256, 0, stream>>>(cnt, N_ATOMS);
    k_count<<<dim3((N_BONDS + 255) / 256), 256, 0, stream>>>(b2a, cnt);
    k_scan<<<dim3(1), 1024, 0, stream>>>(cnt, offs);
    k_zero<<<dim3((N_ATOMS + 255) / 256), 256, 0, stream>>>(pos, N_ATOMS);
    // pos = offs copy via scan output: reuse k_scan result; copy offs->pos
    hipMemcpyAsync(pos, offs, (size_t)N_ATOMS * 4, hipMemcpyDeviceToDevice, stream);
    k_scatter<<<dim3((N_BONDS + 255) / 256), 256, 0, stream>>>(b2a, pos, csr);

    const dim3 gB(gemm_grid(N_BONDS));
    // message = relu(f_bonds @ W_i)
    gemm_bt<1, 0><<<gB, 256, 0, stream>>>(fbpad, KB_PAD, pre, WcT, KC, nullptr,
                                          message, N_BONDS, KB_PAD);
    for (int d = 0; d < DEPTH - 1; ++d) {
        k_pre_g<<<dim3((N_ATOMS + 3) / 4), 256, 0, stream>>>(
            message, a2b, csr, offs, b2revb, pre);
        gemm_bt<1, 0><<<gB, 256, 0, stream>>>(fbpad, KB_PAD, pre, WcT, KC, nullptr,
                                              message, N_BONDS, KC);
    }
    k_amsg<<<dim3(N_ATOMS / 4), 256, 0, stream>>>(message, a2b, ain);
    k_atomfill<<<dim3((N_ATOMS * (KC - HIDDEN) + 255) / 256), 256, 0, stream>>>(f_atoms, ain, flag);
    gemm_bt<0, 1><<<dim3(gemm_grid(N_ATOMS)), 256, 0, stream>>>(
        ain, KC, nullptr, WoT, KC, biasB, ah, N_ATOMS, KC);
    k_mean<<<dim3(N_MOLS), 256, 0, stream>>>(ah, mol_ids, d_out, flag);
}